// Round 6
// baseline (472.314 us; speedup 1.0000x reference)
//
#include <hip/hip_runtime.h>
#include <hip/hip_bf16.h>
#include <stdint.h>

#define D_ 32
#define H_ 128
#define W_ 128
#define NCIN 16
#define NCOUT 32
#define NVOX 200000
#define NB 4
#define PD (D_ + 4)
#define PH (H_ + 4)
#define PW (W_ + 4)

// spatial tiles for locality buckets
#define TZ 8
#define TY 16
#define TX 8
#define NTZ (D_ / TZ)                  // 4
#define NTY (H_ / TY)                  // 8
#define NTX (W_ / TX)                  // 16
#define NTILES (NB * NTZ * NTY * NTX)  // 2048
#define NKEY (NTILES * 27)             // 55296

#define NCHUNK 64                      // 64 K-chunks of K=32 (2 cells each); chunk 63 = zero pad
#define MAXU 32768
#define MAIN_BLOCKS 2048
#define NWAVES (MAIN_BLOCKS * 4)       // 8192

typedef __attribute__((ext_vector_type(8))) short bf16x8;
typedef __attribute__((ext_vector_type(4))) float f32x4;

__device__ __forceinline__ int vox_off(int b, int z, int y, int x) {
    return ((((b * PD + (z + 2)) * PH + (y + 2)) * PW + (x + 2))) * NCIN;
}
__device__ __forceinline__ int cls_of(int z, int y, int x) {
    int cz = (z == 0) ? 0 : ((z == D_ - 1) ? 2 : 1);
    int cy = (y == 0) ? 0 : ((y == H_ - 1) ? 2 : 1);
    int cx = (x == 0) ? 0 : ((x == W_ - 1) ? 2 : 1);
    return (cz * 3 + cy) * 3 + cx;
}
__device__ __forceinline__ int tile_of(int b, int z, int y, int x) {
    return ((b * NTZ + (z / TZ)) * NTY + (y / TY)) * NTX + (x / TX);
}

// ---------------------------------------------------------------------------
// Combined 5x5x5 weights, 27 boundary classes, packed in MFMA B-fragment
// layout: WcB[cls][chunk][lane][j] ; k=(lane>>4)*8+j ; cell=k>>4 ; ci=k&15 ;
// cf=lane&15 ; delta = 2*chunk + cell (>=125 -> zero).
// ---------------------------------------------------------------------------
__global__ void wc_pack_kernel(const float* __restrict__ W1, const float* __restrict__ W2,
                               __hip_bfloat16* __restrict__ WcB) {
    int blk = blockIdx.x;            // cls*NCHUNK + c
    int cls = blk / NCHUNK, c = blk % NCHUNK;
    int t = threadIdx.x;             // 512 = 64 lanes * 8 j
    int l = t >> 3, j = t & 7;
    int k = (l >> 4) * 8 + j;
    int ld = k >> 4, ci = k & 15, cf = l & 15;
    int delta = 2 * c + ld;
    float acc = 0.f;
    if (delta < 125) {
        int sz = delta / 25, sy = (delta / 5) % 5, sx = delta % 5;
        int cz = cls / 9, cy = (cls / 3) % 3, cx = cls % 3;
        for (int k1z = 0; k1z < 3; ++k1z) {
            int k2z = sz - k1z;
            if (k2z < 0 || k2z > 2) continue;
            if ((cz == 0 && k2z == 0) || (cz == 2 && k2z == 2)) continue;
            for (int k1y = 0; k1y < 3; ++k1y) {
                int k2y = sy - k1y;
                if (k2y < 0 || k2y > 2) continue;
                if ((cy == 0 && k2y == 0) || (cy == 2 && k2y == 2)) continue;
                for (int k1x = 0; k1x < 3; ++k1x) {
                    int k2x = sx - k1x;
                    if (k2x < 0 || k2x > 2) continue;
                    if ((cx == 0 && k2x == 0) || (cx == 2 && k2x == 2)) continue;
                    const float* w1 = W1 + ((k1z*3 + k1y)*3 + k1x) * (NCIN*NCOUT) + ci * NCOUT;
                    const float* w2 = W2 + ((k2z*3 + k2y)*3 + k2x) * (NCOUT*NCIN) + cf;
                    #pragma unroll
                    for (int cm = 0; cm < NCOUT; ++cm)
                        acc = fmaf(w1[cm], w2[cm * NCIN], acc);
                }
            }
        }
    }
    WcB[(size_t)blk * 512 + t] = __float2bfloat16(acc);
}

// ---------------------------------------------------------------------------
// Scatter features into padded bf16 dense grid + per-(tile,cls) histogram.
// ---------------------------------------------------------------------------
__global__ void scatter_count_kernel(const float* __restrict__ feats,
                                     const int* __restrict__ coors,
                                     __hip_bfloat16* __restrict__ dense,
                                     unsigned int* __restrict__ cnt) {
    int t = blockIdx.x * blockDim.x + threadIdx.x;
    if (t >= NVOX * NCIN) return;
    int v = t >> 4, c = t & 15;
    const int4* c4 = (const int4*)coors;
    int4 q = c4[v];
    dense[vox_off(q.x, q.y, q.z, q.w) + c] = __float2bfloat16(feats[t]);
    if (c == 0) {
        int key = tile_of(q.x, q.y, q.z, q.w) * 27 + cls_of(q.y, q.z, q.w);
        atomicAdd(&cnt[key], 1u);
    }
}

// ---------------------------------------------------------------------------
// Atomic allocator: per key, grab a base in list[] and emit supergroup units
// (<=64 voxels, uniform cls). ctrs[0]=queue (init NWAVES), [1]=list alloc,
// [2]=unit count. No scan needed; output values are grouping-invariant.
// ---------------------------------------------------------------------------
__global__ void alloc_kernel(const unsigned int* __restrict__ cnt,
                             unsigned int* __restrict__ cur,
                             unsigned int* __restrict__ ctrs,
                             uint2* __restrict__ gdesc) {
    int key = blockIdx.x * blockDim.x + threadIdx.x;
    if (key >= NKEY) return;
    if (key == 0) ctrs[0] = NWAVES;
    unsigned c = cnt[key];
    if (!c) return;
    unsigned base = atomicAdd(&ctrs[1], c);
    cur[key] = base;
    unsigned ng = (c + 63) >> 6;
    unsigned gpos = atomicAdd(&ctrs[2], ng);
    unsigned cls = (unsigned)(key % 27);
    for (unsigned i = 0, o = 0; i < ng && gpos + i < MAXU; ++i, o += 64) {
        unsigned cc = c - o; if (cc > 64) cc = 64;
        gdesc[gpos + i] = make_uint2(base + o, cls | (cc << 16));
    }
}

__global__ void bucket_kernel(const int* __restrict__ coors,
                              unsigned int* __restrict__ cur,
                              unsigned int* __restrict__ list) {
    int v = blockIdx.x * blockDim.x + threadIdx.x;
    if (v >= NVOX) return;
    const int4* c4 = (const int4*)coors;
    int4 q = c4[v];
    int key = tile_of(q.x, q.y, q.z, q.w) * 27 + cls_of(q.y, q.z, q.w);
    unsigned pos = atomicAdd(&cur[key], 1u);
    list[pos] = (unsigned)v;
}

// ---------------------------------------------------------------------------
// Main gather-GEMM. One wave per unit (<=64 voxels, 4 MFMA row-groups sharing
// one B load). Static XCD-partitioned first unit + atomic work-stealing.
// Explicit depth-2 software pipeline, named registers only.
// ---------------------------------------------------------------------------
__global__ void __launch_bounds__(256, 4) main_kernel(
        const int* __restrict__ coors, const __hip_bfloat16* __restrict__ dense,
        const __hip_bfloat16* __restrict__ WcB, const uint2* __restrict__ gdesc,
        unsigned int* __restrict__ ctrs, const unsigned int* __restrict__ list,
        float* __restrict__ out) {
    __shared__ int lut[2 * NCHUNK];
    int t = threadIdx.x;
    if (t < 2 * NCHUNK) {
        int d = t, rel = 0;
        if (d < 125) {
            int dz = d / 25, dy = (d / 5) % 5, dx = d % 5;
            rel = (((dz - 2) * PH + (dy - 2)) * PW + (dx - 2)) * NCIN;
        }
        lut[t] = rel;
    }
    __syncthreads();
    unsigned nunits = ctrs[2];
    int w = t >> 6, lane = t & 63;
    int col = lane & 15, halfsel = (lane >> 4) & 1, dsel = lane >> 5;
    int bid = blockIdx.x;
    // static first unit: per-XCD contiguous ranges for L2 tile locality
    unsigned u = (unsigned)((bid & 7) * (NWAVES / 8) + (bid >> 3) * 4 + w);
    const int4* c4 = (const int4*)coors;

    while (u < nunits) {
        uint2 dsc = gdesc[u];
        unsigned off = dsc.x;
        int cls = (int)(dsc.y & 0xffffu);
        int cnt = (int)(dsc.y >> 16);

        int r0 = min(col, cnt - 1);
        int r1 = min(16 + col, cnt - 1);
        int r2 = min(32 + col, cnt - 1);
        int r3 = min(48 + col, cnt - 1);
        unsigned v0 = list[off + r0], v1 = list[off + r1];
        unsigned v2 = list[off + r2], v3 = list[off + r3];
        int4 q0 = c4[v0], q1 = c4[v1], q2 = c4[v2], q3 = c4[v3];
        int base0 = vox_off(q0.x, q0.y, q0.z, q0.w) + halfsel * 8;
        int base1 = vox_off(q1.x, q1.y, q1.z, q1.w) + halfsel * 8;
        int base2 = vox_off(q2.x, q2.y, q2.z, q2.w) + halfsel * 8;
        int base3 = vox_off(q3.x, q3.y, q3.z, q3.w) + halfsel * 8;
        const bf16x8* bq = (const bf16x8*)WcB + (size_t)cls * (NCHUNK * 64) + lane;

        f32x4 acc0 = {0.f, 0.f, 0.f, 0.f};
        f32x4 acc1 = {0.f, 0.f, 0.f, 0.f};
        f32x4 acc2 = {0.f, 0.f, 0.f, 0.f};
        f32x4 acc3 = {0.f, 0.f, 0.f, 0.f};
        bf16x8 bA, a0A, a1A, a2A, a3A, bB, a0B, a1B, a2B, a3B;

#define LOADS(c_, BV, A0, A1, A2, A3) { \
        int cc_ = (c_) & (NCHUNK - 1); \
        int rel_ = lut[2 * cc_ + dsel]; \
        A0 = *(const bf16x8*)(dense + (base0 + rel_)); \
        A1 = *(const bf16x8*)(dense + (base1 + rel_)); \
        A2 = *(const bf16x8*)(dense + (base2 + rel_)); \
        A3 = *(const bf16x8*)(dense + (base3 + rel_)); \
        BV = bq[cc_ * 64]; }

        LOADS(0, bA, a0A, a1A, a2A, a3A)
        LOADS(1, bB, a0B, a1B, a2B, a3B)
        for (int c = 0; c < NCHUNK; c += 2) {
            acc0 = __builtin_amdgcn_mfma_f32_16x16x32_bf16(a0A, bA, acc0, 0, 0, 0);
            acc1 = __builtin_amdgcn_mfma_f32_16x16x32_bf16(a1A, bA, acc1, 0, 0, 0);
            acc2 = __builtin_amdgcn_mfma_f32_16x16x32_bf16(a2A, bA, acc2, 0, 0, 0);
            acc3 = __builtin_amdgcn_mfma_f32_16x16x32_bf16(a3A, bA, acc3, 0, 0, 0);
            LOADS(c + 2, bA, a0A, a1A, a2A, a3A)
            acc0 = __builtin_amdgcn_mfma_f32_16x16x32_bf16(a0B, bB, acc0, 0, 0, 0);
            acc1 = __builtin_amdgcn_mfma_f32_16x16x32_bf16(a1B, bB, acc1, 0, 0, 0);
            acc2 = __builtin_amdgcn_mfma_f32_16x16x32_bf16(a2B, bB, acc2, 0, 0, 0);
            acc3 = __builtin_amdgcn_mfma_f32_16x16x32_bf16(a3B, bB, acc3, 0, 0, 0);
            LOADS(c + 3, bB, a0B, a1B, a2B, a3B)
        }
#undef LOADS

        int rowq = (lane >> 4) * 4;
#define WRITEJ(j_, ACC) { \
        int orow_ = 16 * (j_) + rowq; \
        _Pragma("unroll") \
        for (int reg = 0; reg < 4; ++reg) { \
            int rr_ = orow_ + reg; \
            if (rr_ < cnt) { \
                unsigned vo_ = list[off + rr_]; \
                out[(size_t)vo_ * 16 + col] = ACC[reg]; \
            } } }
        WRITEJ(0, acc0)
        WRITEJ(1, acc1)
        WRITEJ(2, acc2)
        WRITEJ(3, acc3)
#undef WRITEJ

        unsigned nu = 0;
        if (lane == 0) nu = atomicAdd(&ctrs[0], 1u);
        u = (unsigned)__shfl((int)nu, 0);
    }
}

extern "C" void kernel_launch(void* const* d_in, const int* in_sizes, int n_in,
                              void* d_out, int out_size, void* d_ws, size_t ws_size,
                              hipStream_t stream) {
    const float* features = (const float*)d_in[0];
    const int*   coors    = (const int*)d_in[1];
    const float* W1       = (const float*)d_in[2];
    const float* W2       = (const float*)d_in[3];
    float* out = (float*)d_out;

    const size_t dense_elems = (size_t)NB * PD * PH * PW * NCIN;
    const size_t dense_bytes = dense_elems * sizeof(__hip_bfloat16);     // 80.3 MB
    char* p = (char*)d_ws;
    __hip_bfloat16* dense = (__hip_bfloat16*)p;
    p += ((dense_bytes + 255) / 256) * 256;
    __hip_bfloat16* WcB = (__hip_bfloat16*)p;                            // 1.77 MB
    p += (((size_t)27 * NCHUNK * 512 * 2 + 255) / 256) * 256;
    unsigned int* cnt = (unsigned int*)p;                                // NKEY*4
    unsigned int* ctrs = cnt + NKEY;                                     // 3 u32 (same memset)
    p += (((size_t)NKEY * 4 + 256 + 255) / 256) * 256;
    unsigned int* cur = (unsigned int*)p;                                // NKEY*4
    p += (((size_t)NKEY * 4 + 255) / 256) * 256;
    unsigned int* list = (unsigned int*)p;                               // NVOX*4
    p += (((size_t)NVOX * 4 + 255) / 256) * 256;
    uint2* gdesc = (uint2*)p;                                            // MAXU*8

    hipMemsetAsync(dense, 0, dense_bytes, stream);
    hipMemsetAsync(cnt, 0, (size_t)NKEY * 4 + 256, stream);

    wc_pack_kernel<<<27 * NCHUNK, 512, 0, stream>>>(W1, W2, WcB);
    scatter_count_kernel<<<(NVOX * NCIN + 255) / 256, 256, 0, stream>>>(features, coors, dense, cnt);
    alloc_kernel<<<(NKEY + 255) / 256, 256, 0, stream>>>(cnt, cur, ctrs, gdesc);
    bucket_kernel<<<(NVOX + 255) / 256, 256, 0, stream>>>(coors, cur, list);
    main_kernel<<<MAIN_BLOCKS, 256, 0, stream>>>(coors, dense, WcB, gdesc, ctrs, list, out);
}

// Round 7
// 276.650 us; speedup vs baseline: 1.7073x; 1.7073x over previous
//
#include <hip/hip_runtime.h>
#include <hip/hip_bf16.h>
#include <stdint.h>

#define D_ 32
#define H_ 128
#define W_ 128
#define NCIN 16
#define NCOUT 32
#define NVOX 200000
#define NB 4
#define PD (D_ + 4)
#define PH (H_ + 4)
#define PW (W_ + 4)

// spatial tiles for locality buckets
#define TZ 8
#define TY 16
#define TX 8
#define NTZ (D_ / TZ)                  // 4
#define NTY (H_ / TY)                  // 8
#define NTX (W_ / TX)                  // 16
#define NTILES (NB * NTZ * NTY * NTX)  // 2048
#define NKEY (NTILES * 27)             // 55296

#define NCHUNK 64                      // 64 K-chunks of K=32 (2 cells each); chunk 63 = zero pad
#define MAXU 32768
#define MAIN_BLOCKS 1024
#define NWAVES (MAIN_BLOCKS * 4)       // 4096 <= nunits (~5000) so stealing engages

typedef __attribute__((ext_vector_type(8))) short bf16x8;
typedef __attribute__((ext_vector_type(4))) float f32x4;

__device__ __forceinline__ int vox_off(int b, int z, int y, int x) {
    return ((((b * PD + (z + 2)) * PH + (y + 2)) * PW + (x + 2))) * NCIN;
}
__device__ __forceinline__ int cls_of(int z, int y, int x) {
    int cz = (z == 0) ? 0 : ((z == D_ - 1) ? 2 : 1);
    int cy = (y == 0) ? 0 : ((y == H_ - 1) ? 2 : 1);
    int cx = (x == 0) ? 0 : ((x == W_ - 1) ? 2 : 1);
    return (cz * 3 + cy) * 3 + cx;
}
__device__ __forceinline__ int tile_of(int b, int z, int y, int x) {
    return ((b * NTZ + (z / TZ)) * NTY + (y / TY)) * NTX + (x / TX);
}

// ---------------------------------------------------------------------------
// Stage A: pairwise products P[k1][k2][ci][cf] = sum_cm W1[k1,ci,cm]*W2[k2,cm,cf]
// from LDS-staged weights. Replaces the scalar-load elephant in old wc_pack.
// ---------------------------------------------------------------------------
__global__ void wc_p_kernel(const float* __restrict__ W1, const float* __restrict__ W2,
                            float* __restrict__ P) {
    int k12 = blockIdx.x;            // k1*27 + k2
    int k1 = k12 / 27, k2 = k12 % 27;
    __shared__ float w1s[512], w2s[512];
    int t = threadIdx.x;             // 256
    w1s[t] = W1[k1 * 512 + t];       w1s[t + 256] = W1[k1 * 512 + 256 + t];
    w2s[t] = W2[k2 * 512 + t];       w2s[t + 256] = W2[k2 * 512 + 256 + t];
    __syncthreads();
    int ci = t >> 4, cf = t & 15;
    float acc = 0.f;
    #pragma unroll
    for (int cm = 0; cm < 32; ++cm)
        acc = fmaf(w1s[ci * 32 + cm], w2s[cm * 16 + cf], acc);
    P[k12 * 256 + t] = acc;
}

// ---------------------------------------------------------------------------
// Stage B: combined 5x5x5 weights, 27 boundary classes, MFMA B-fragment layout:
// WcB[cls][chunk][lane][j] ; k=(lane>>4)*8+j ; cell=k>>4 ; ci=k&15 ; cf=lane&15;
// delta = 2*chunk + cell (>=125 -> zero). Each output = sum of ~6 P entries.
// ---------------------------------------------------------------------------
__global__ void wc_pack2_kernel(const float* __restrict__ P, __hip_bfloat16* __restrict__ WcB) {
    int blk = blockIdx.x;            // cls*NCHUNK + c
    int cls = blk / NCHUNK, c = blk % NCHUNK;
    int t = threadIdx.x;             // 512
    int l = t >> 3, j = t & 7;
    int k = (l >> 4) * 8 + j;
    int ld = k >> 4, ci = k & 15, cf = l & 15;
    int delta = 2 * c + ld;
    float acc = 0.f;
    if (delta < 125) {
        int sz = delta / 25, sy = (delta / 5) % 5, sx = delta % 5;
        int cz = cls / 9, cy = (cls / 3) % 3, cx = cls % 3;
        for (int k1z = 0; k1z < 3; ++k1z) {
            int k2z = sz - k1z;
            if (k2z < 0 || k2z > 2) continue;
            if ((cz == 0 && k2z == 0) || (cz == 2 && k2z == 2)) continue;
            for (int k1y = 0; k1y < 3; ++k1y) {
                int k2y = sy - k1y;
                if (k2y < 0 || k2y > 2) continue;
                if ((cy == 0 && k2y == 0) || (cy == 2 && k2y == 2)) continue;
                for (int k1x = 0; k1x < 3; ++k1x) {
                    int k2x = sx - k1x;
                    if (k2x < 0 || k2x > 2) continue;
                    if ((cx == 0 && k2x == 0) || (cx == 2 && k2x == 2)) continue;
                    int k1 = (k1z * 3 + k1y) * 3 + k1x;
                    int k2 = (k2z * 3 + k2y) * 3 + k2x;
                    acc += P[(k1 * 27 + k2) * 256 + ci * 16 + cf];
                }
            }
        }
    }
    WcB[(size_t)blk * 512 + t] = __float2bfloat16(acc);
}

// ---------------------------------------------------------------------------
// Scatter features into padded bf16 dense grid + per-(tile,cls) histogram.
// ---------------------------------------------------------------------------
__global__ void scatter_count_kernel(const float* __restrict__ feats,
                                     const int* __restrict__ coors,
                                     __hip_bfloat16* __restrict__ dense,
                                     unsigned int* __restrict__ cnt) {
    int t = blockIdx.x * blockDim.x + threadIdx.x;
    if (t >= NVOX * NCIN) return;
    int v = t >> 4, c = t & 15;
    const int4* c4 = (const int4*)coors;
    int4 q = c4[v];
    dense[vox_off(q.x, q.y, q.z, q.w) + c] = __float2bfloat16(feats[t]);
    if (c == 0) {
        int key = tile_of(q.x, q.y, q.z, q.w) * 27 + cls_of(q.y, q.z, q.w);
        atomicAdd(&cnt[key], 1u);
    }
}

// Per-tile totals: unit count (ceil per cls / 64) and voxel count.
__global__ void tile_scan_kernel(const unsigned int* __restrict__ cnt,
                                 unsigned int* __restrict__ ucnt,
                                 unsigned int* __restrict__ vcnt) {
    int tile = blockIdx.x * blockDim.x + threadIdx.x;
    if (tile >= NTILES) return;
    unsigned uu = 0, vv = 0;
    for (int c = 0; c < 27; ++c) {
        unsigned cc = cnt[tile * 27 + c];
        uu += (cc + 63) >> 6;
        vv += cc;
    }
    ucnt[tile] = uu;
    vcnt[tile] = vv;
}

// One-block parallel exclusive scan over 2048 tiles (2 per thread).
__global__ void scan2_kernel(const unsigned int* __restrict__ ucnt,
                             const unsigned int* __restrict__ vcnt,
                             unsigned int* __restrict__ ubase,
                             unsigned int* __restrict__ vbase,
                             unsigned int* __restrict__ ctrs) {
    __shared__ unsigned su[1024], sv[1024];
    int t = threadIdx.x;
    unsigned u0 = ucnt[2 * t], u1 = ucnt[2 * t + 1];
    unsigned v0 = vcnt[2 * t], v1 = vcnt[2 * t + 1];
    su[t] = u0 + u1; sv[t] = v0 + v1;
    __syncthreads();
    for (int o = 1; o < 1024; o <<= 1) {
        unsigned au = 0, av = 0;
        if (t >= o) { au = su[t - o]; av = sv[t - o]; }
        __syncthreads();
        su[t] += au; sv[t] += av;
        __syncthreads();
    }
    unsigned eu = su[t] - (u0 + u1);   // exclusive prefix
    unsigned ev = sv[t] - (v0 + v1);
    ubase[2 * t] = eu; ubase[2 * t + 1] = eu + u0;
    vbase[2 * t] = ev; vbase[2 * t + 1] = ev + v0;
    if (t == 1023) { ctrs[2] = su[1023]; ctrs[0] = NWAVES; }
}

// Per tile: write per-key list offsets (cur) and emit units in tile-major order.
__global__ void emit_kernel(const unsigned int* __restrict__ cnt,
                            const unsigned int* __restrict__ ubase,
                            const unsigned int* __restrict__ vbase,
                            unsigned int* __restrict__ cur,
                            uint2* __restrict__ gdesc) {
    int tile = blockIdx.x * blockDim.x + threadIdx.x;
    if (tile >= NTILES) return;
    unsigned uo = ubase[tile], vo = vbase[tile];
    for (int c = 0; c < 27; ++c) {
        int key = tile * 27 + c;
        unsigned cc = cnt[key];
        cur[key] = vo;
        for (unsigned o = 0; o < cc; o += 64) {
            unsigned r = cc - o; if (r > 64) r = 64;
            if (uo < MAXU) gdesc[uo] = make_uint2(vo + o, (unsigned)c | (r << 16));
            ++uo;
        }
        vo += cc;
    }
}

__global__ void bucket_kernel(const int* __restrict__ coors,
                              unsigned int* __restrict__ cur,
                              unsigned int* __restrict__ list) {
    int v = blockIdx.x * blockDim.x + threadIdx.x;
    if (v >= NVOX) return;
    const int4* c4 = (const int4*)coors;
    int4 q = c4[v];
    int key = tile_of(q.x, q.y, q.z, q.w) * 27 + cls_of(q.y, q.z, q.w);
    unsigned pos = atomicAdd(&cur[key], 1u);
    list[pos] = (unsigned)v;
}

// ---------------------------------------------------------------------------
// Main gather-GEMM. Persistent waves; one unit (<=64 voxels, uniform cls,
// 4 MFMA row-groups sharing one B load) at a time; static XCD-partitioned
// first unit then atomic stealing (queue init NWAVES <= nunits, so it works).
// Depth-2 software pipeline, named registers only. Body identical to the
// numerically-verified round-6 kernel.
// ---------------------------------------------------------------------------
__global__ void __launch_bounds__(256, 4) main_kernel(
        const int* __restrict__ coors, const __hip_bfloat16* __restrict__ dense,
        const __hip_bfloat16* __restrict__ WcB, const uint2* __restrict__ gdesc,
        unsigned int* __restrict__ ctrs, const unsigned int* __restrict__ list,
        float* __restrict__ out) {
    __shared__ int lut[2 * NCHUNK];
    int t = threadIdx.x;
    if (t < 2 * NCHUNK) {
        int d = t, rel = 0;
        if (d < 125) {
            int dz = d / 25, dy = (d / 5) % 5, dx = d % 5;
            rel = (((dz - 2) * PH + (dy - 2)) * PW + (dx - 2)) * NCIN;
        }
        lut[t] = rel;
    }
    __syncthreads();
    unsigned nunits = ctrs[2];
    int w = t >> 6, lane = t & 63;
    int col = lane & 15, halfsel = (lane >> 4) & 1, dsel = lane >> 5;
    int bid = blockIdx.x;
    // static first unit: per-XCD contiguous ranges over tile-major unit order
    unsigned u = (unsigned)((bid & 7) * (NWAVES / 8) + (bid >> 3) * 4 + w);
    const int4* c4 = (const int4*)coors;

    while (u < nunits) {
        uint2 dsc = gdesc[u];
        unsigned off = dsc.x;
        int cls = (int)(dsc.y & 0xffffu);
        int cnt = (int)(dsc.y >> 16);

        int r0 = min(col, cnt - 1);
        int r1 = min(16 + col, cnt - 1);
        int r2 = min(32 + col, cnt - 1);
        int r3 = min(48 + col, cnt - 1);
        unsigned v0 = list[off + r0], v1 = list[off + r1];
        unsigned v2 = list[off + r2], v3 = list[off + r3];
        int4 q0 = c4[v0], q1 = c4[v1], q2 = c4[v2], q3 = c4[v3];
        int base0 = vox_off(q0.x, q0.y, q0.z, q0.w) + halfsel * 8;
        int base1 = vox_off(q1.x, q1.y, q1.z, q1.w) + halfsel * 8;
        int base2 = vox_off(q2.x, q2.y, q2.z, q2.w) + halfsel * 8;
        int base3 = vox_off(q3.x, q3.y, q3.z, q3.w) + halfsel * 8;
        const bf16x8* bq = (const bf16x8*)WcB + (size_t)cls * (NCHUNK * 64) + lane;

        f32x4 acc0 = {0.f, 0.f, 0.f, 0.f};
        f32x4 acc1 = {0.f, 0.f, 0.f, 0.f};
        f32x4 acc2 = {0.f, 0.f, 0.f, 0.f};
        f32x4 acc3 = {0.f, 0.f, 0.f, 0.f};
        bf16x8 bA, a0A, a1A, a2A, a3A, bB, a0B, a1B, a2B, a3B;

#define LOADS(c_, BV, A0, A1, A2, A3) { \
        int cc_ = (c_) & (NCHUNK - 1); \
        int rel_ = lut[2 * cc_ + dsel]; \
        A0 = *(const bf16x8*)(dense + (base0 + rel_)); \
        A1 = *(const bf16x8*)(dense + (base1 + rel_)); \
        A2 = *(const bf16x8*)(dense + (base2 + rel_)); \
        A3 = *(const bf16x8*)(dense + (base3 + rel_)); \
        BV = bq[cc_ * 64]; }

        LOADS(0, bA, a0A, a1A, a2A, a3A)
        LOADS(1, bB, a0B, a1B, a2B, a3B)
        for (int c = 0; c < NCHUNK; c += 2) {
            acc0 = __builtin_amdgcn_mfma_f32_16x16x32_bf16(a0A, bA, acc0, 0, 0, 0);
            acc1 = __builtin_amdgcn_mfma_f32_16x16x32_bf16(a1A, bA, acc1, 0, 0, 0);
            acc2 = __builtin_amdgcn_mfma_f32_16x16x32_bf16(a2A, bA, acc2, 0, 0, 0);
            acc3 = __builtin_amdgcn_mfma_f32_16x16x32_bf16(a3A, bA, acc3, 0, 0, 0);
            LOADS(c + 2, bA, a0A, a1A, a2A, a3A)
            acc0 = __builtin_amdgcn_mfma_f32_16x16x32_bf16(a0B, bB, acc0, 0, 0, 0);
            acc1 = __builtin_amdgcn_mfma_f32_16x16x32_bf16(a1B, bB, acc1, 0, 0, 0);
            acc2 = __builtin_amdgcn_mfma_f32_16x16x32_bf16(a2B, bB, acc2, 0, 0, 0);
            acc3 = __builtin_amdgcn_mfma_f32_16x16x32_bf16(a3B, bB, acc3, 0, 0, 0);
            LOADS(c + 3, bB, a0B, a1B, a2B, a3B)
        }
#undef LOADS

        int rowq = (lane >> 4) * 4;
#define WRITEJ(j_, ACC) { \
        int orow_ = 16 * (j_) + rowq; \
        _Pragma("unroll") \
        for (int reg = 0; reg < 4; ++reg) { \
            int rr_ = orow_ + reg; \
            if (rr_ < cnt) { \
                unsigned vo_ = list[off + rr_]; \
                out[(size_t)vo_ * 16 + col] = ACC[reg]; \
            } } }
        WRITEJ(0, acc0)
        WRITEJ(1, acc1)
        WRITEJ(2, acc2)
        WRITEJ(3, acc3)
#undef WRITEJ

        unsigned nu = 0;
        if (lane == 0) nu = atomicAdd(&ctrs[0], 1u);
        u = (unsigned)__shfl((int)nu, 0);
    }
}

extern "C" void kernel_launch(void* const* d_in, const int* in_sizes, int n_in,
                              void* d_out, int out_size, void* d_ws, size_t ws_size,
                              hipStream_t stream) {
    const float* features = (const float*)d_in[0];
    const int*   coors    = (const int*)d_in[1];
    const float* W1       = (const float*)d_in[2];
    const float* W2       = (const float*)d_in[3];
    float* out = (float*)d_out;

    const size_t dense_elems = (size_t)NB * PD * PH * PW * NCIN;
    const size_t dense_bytes = dense_elems * sizeof(__hip_bfloat16);     // 80.3 MB
    char* p = (char*)d_ws;
    __hip_bfloat16* dense = (__hip_bfloat16*)p;
    p += ((dense_bytes + 255) / 256) * 256;
    __hip_bfloat16* WcB = (__hip_bfloat16*)p;                            // 1.77 MB
    p += (((size_t)27 * NCHUNK * 512 * 2 + 255) / 256) * 256;
    unsigned int* cnt = (unsigned int*)p;                                // NKEY*4
    p += (((size_t)NKEY * 4 + 255) / 256) * 256;
    unsigned int* cur = (unsigned int*)p;                                // NKEY*4
    p += (((size_t)NKEY * 4 + 255) / 256) * 256;
    unsigned int* ucnt = (unsigned int*)p;  p += 8192;                   // NTILES*4
    unsigned int* vcnt = (unsigned int*)p;  p += 8192;
    unsigned int* ubase = (unsigned int*)p; p += 8192;
    unsigned int* vbase = (unsigned int*)p; p += 8192;
    unsigned int* ctrs = (unsigned int*)p;  p += 256;
    unsigned int* list = (unsigned int*)p;                               // NVOX*4 = 800000
    float* P = (float*)list;                // stage-A scratch aliases list (746496 B <= 800000)
    p += (((size_t)NVOX * 4 + 255) / 256) * 256;
    uint2* gdesc = (uint2*)p;                                            // MAXU*8

    hipMemsetAsync(dense, 0, dense_bytes, stream);
    hipMemsetAsync(cnt, 0, (size_t)NKEY * 4, stream);

    wc_p_kernel<<<729, 256, 0, stream>>>(W1, W2, P);
    wc_pack2_kernel<<<27 * NCHUNK, 512, 0, stream>>>(P, WcB);
    scatter_count_kernel<<<(NVOX * NCIN + 255) / 256, 256, 0, stream>>>(features, coors, dense, cnt);
    tile_scan_kernel<<<NTILES / 256, 256, 0, stream>>>(cnt, ucnt, vcnt);
    scan2_kernel<<<1, 1024, 0, stream>>>(ucnt, vcnt, ubase, vbase, ctrs);
    emit_kernel<<<NTILES / 256, 256, 0, stream>>>(cnt, ubase, vbase, cur, gdesc);
    bucket_kernel<<<(NVOX + 255) / 256, 256, 0, stream>>>(coors, cur, list);
    main_kernel<<<MAIN_BLOCKS, 256, 0, stream>>>(coors, dense, WcB, gdesc, ctrs, list, out);
}